// Round 2
// baseline (66.644 us; speedup 1.0000x reference)
//
#include <hip/hip_runtime.h>
#include <hip/hip_bf16.h>

typedef __attribute__((ext_vector_type(8))) short short8;
typedef __attribute__((ext_vector_type(4))) float f32x4;
typedef __attribute__((ext_vector_type(4))) int   i32x4;

#define IN_F   4096
#define OUT_F  16384
#define NG     32      // groups per row (4096/128)
#define GROUP  128

// f32 -> bf16 with round-to-nearest-even
static __device__ __forceinline__ short f2bf(float f) {
    union { float f; unsigned u; } c; c.f = f;
    unsigned u = c.u;
    u += 0x7FFF + ((u >> 16) & 1);
    return (short)(u >> 16);
}

// int8-range value -> bf16 (exact: |v| <= 127 fits bf16's 8-bit significand)
static __device__ __forceinline__ short i2bf(int v) {
    union { float f; unsigned u; } c; c.f = (float)v;
    return (short)(c.u >> 16);
}

// Block: 512 threads = 8 waves. Block owns 32 output cols; wave w owns k in [w*512, w*512+512).
// Grid: 16384/32 = 512 blocks -> 2 blocks/CU, 16 waves/CU.
__global__ __launch_bounds__(512, 4)
void qlin_kernel(const float* __restrict__ x,       // [32][4096] f32 (fp16 promoted)
                 const int*   __restrict__ qw,      // [16384][4096] int32 (int8 values)
                 const float* __restrict__ scales,  // [16384][32] f32
                 const float* __restrict__ bias,    // [16384] f32
                 float*       __restrict__ out)     // [32][16384] f32
{
    const int tid  = threadIdx.x;
    const int wv   = tid >> 6;        // wave 0..7
    const int lane = tid & 63;
    const int l15  = lane & 15;
    const int l4   = lane >> 4;       // 0..3
    const int col0 = blockIdx.x << 5; // 32 cols per block
    const int kb   = wv << 9;         // 512 k per wave

    f32x4 acc[2][2];                  // [mtile][ntile]
#pragma unroll
    for (int m = 0; m < 2; ++m)
#pragma unroll
        for (int n = 0; n < 2; ++n)
            acc[m][n] = (f32x4){0.f, 0.f, 0.f, 0.f};

    const float* xr0 = x + (size_t)l15 * IN_F;
    const float* xr1 = x + (size_t)(l15 + 16) * IN_F;
    const int* wr0 = qw + (size_t)(col0 + l15) * IN_F;
    const int* wr1 = qw + (size_t)(col0 + 16 + l15) * IN_F;

#pragma unroll
    for (int g = 0; g < 4; ++g) {                 // 4 groups of 128 k per wave
        f32x4 ag[2][2];
#pragma unroll
        for (int m = 0; m < 2; ++m)
#pragma unroll
            for (int n = 0; n < 2; ++n)
                ag[m][n] = (f32x4){0.f, 0.f, 0.f, 0.f};

        const int kg = kb + g * GROUP;
#pragma unroll
        for (int s = 0; s < 4; ++s) {             // 4 MFMA K-steps of 32
            const int k = kg + s * 32 + (l4 << 3);
            f32x4 x0a = *(const f32x4*)(xr0 + k);
            f32x4 x0b = *(const f32x4*)(xr0 + k + 4);
            f32x4 x1a = *(const f32x4*)(xr1 + k);
            f32x4 x1b = *(const f32x4*)(xr1 + k + 4);
            i32x4 q0a = *(const i32x4*)(wr0 + k);
            i32x4 q0b = *(const i32x4*)(wr0 + k + 4);
            i32x4 q1a = *(const i32x4*)(wr1 + k);
            i32x4 q1b = *(const i32x4*)(wr1 + k + 4);
            short8 a0, a1, b0, b1;
#pragma unroll
            for (int i = 0; i < 4; ++i) {
                a0[i]     = f2bf(x0a[i]);
                a0[i + 4] = f2bf(x0b[i]);
                a1[i]     = f2bf(x1a[i]);
                a1[i + 4] = f2bf(x1b[i]);
                b0[i]     = i2bf(q0a[i]);
                b0[i + 4] = i2bf(q0b[i]);
                b1[i]     = i2bf(q1a[i]);
                b1[i + 4] = i2bf(q1b[i]);
            }
            ag[0][0] = __builtin_amdgcn_mfma_f32_16x16x32_bf16(a0, b0, ag[0][0], 0, 0, 0);
            ag[1][0] = __builtin_amdgcn_mfma_f32_16x16x32_bf16(a1, b0, ag[1][0], 0, 0, 0);
            ag[0][1] = __builtin_amdgcn_mfma_f32_16x16x32_bf16(a0, b1, ag[0][1], 0, 0, 0);
            ag[1][1] = __builtin_amdgcn_mfma_f32_16x16x32_bf16(a1, b1, ag[1][1], 0, 0, 0);
        }

        const int gi = (kb >> 7) + g;             // global group index = wv*4 + g
        const float s0 = scales[(size_t)(col0 + l15) * NG + gi];
        const float s1 = scales[(size_t)(col0 + 16 + l15) * NG + gi];
#pragma unroll
        for (int m = 0; m < 2; ++m)
#pragma unroll
            for (int r = 0; r < 4; ++r) {
                acc[m][0][r] += s0 * ag[m][0][r];
                acc[m][1][r] += s1 * ag[m][1][r];
            }
    }

    // Cross-wave K reduction through LDS, then bias + store.
    __shared__ float red[8][32][32];              // 32 KB
#pragma unroll
    for (int m = 0; m < 2; ++m)
#pragma unroll
        for (int n = 0; n < 2; ++n)
#pragma unroll
            for (int r = 0; r < 4; ++r)
                red[wv][m * 16 + l4 * 4 + r][n * 16 + l15] = acc[m][n][r];
    __syncthreads();

    for (int t = tid; t < 1024; t += 512) {
        const int b = t >> 5;
        const int c = t & 31;
        float s = 0.f;
#pragma unroll
        for (int w = 0; w < 8; ++w) s += red[w][b][c];
        s += bias[col0 + c];
        out[(size_t)b * OUT_F + col0 + c] = s;
    }
}

extern "C" void kernel_launch(void* const* d_in, const int* in_sizes, int n_in,
                              void* d_out, int out_size, void* d_ws, size_t ws_size,
                              hipStream_t stream) {
    const float* x      = (const float*)d_in[0];
    const int*   qw     = (const int*)d_in[1];
    const float* scales = (const float*)d_in[2];
    const float* bias   = (const float*)d_in[3];
    float*       out    = (float*)d_out;

    dim3 grid(OUT_F / 32);   // 512 blocks
    dim3 block(512);         // 8 waves
    hipLaunchKernelGGL(qlin_kernel, grid, block, 0, stream,
                       x, qw, scales, bias, out);
}